// Round 14
// baseline (1531.120 us; speedup 1.0000x reference)
//
#include <hip/hip_runtime.h>
#include <stdint.h>

#define THREADS 256
#define ITEMS 16
#define CHUNK (THREADS * ITEMS)
#define COLMASK 0xFFFFFu
#define EDIG 4096      // edge scatter digits = row>>8
#define BR 256         // rows per edge bucket
#define BCAP 4608      // bucket capacity (avg 4096, +8 sigma)
#define BPHYS (BCAP + (BCAP >> 5) + 8)   // swizzled u32 capacity
#define PDIG 1024      // perm MSD digits

// ---------------- threefry2x32, JAX-compatible (20 rounds) ----------------
__host__ __device__ static inline void tf2x32(uint32_t k0, uint32_t k1,
                                              uint32_t x0, uint32_t x1,
                                              uint32_t* o0, uint32_t* o1) {
  uint32_t ks[3] = {k0, k1, k0 ^ k1 ^ 0x1BD11BDAu};
  x0 += ks[0]; x1 += ks[1];
  const uint32_t RA[4] = {13u, 15u, 26u, 6u};
  const uint32_t RB[4] = {17u, 29u, 16u, 24u};
#pragma unroll
  for (int g = 0; g < 5; ++g) {
    const uint32_t* R = (g & 1) ? RB : RA;
#pragma unroll
    for (int j = 0; j < 4; ++j) {
      x0 += x1;
      x1 = (x1 << R[j]) | (x1 >> (32u - R[j]));
      x1 ^= x0;
    }
    x0 += ks[(g + 1) % 3];
    x1 += ks[(g + 2) % 3] + (uint32_t)(g + 1);
  }
  *o0 = x0; *o1 = x1;
}

__device__ static inline uint32_t rbits32(uint32_t ka, uint32_t kb, uint32_t i) {
  uint32_t o0, o1;
  tf2x32(ka, kb, 0u, i, &o0, &o1);
  return o0 ^ o1;
}

// bijective XCD-aware block swizzle (m204 variant; works for any nwg)
__device__ static inline int xcd_swz(int orig, int nwg) {
  int q = nwg >> 3, r = nwg & 7;
  int xcd = orig & 7, idx = orig >> 3;
  return (xcd < r ? xcd * (q + 1) : r * (q + 1) + (xcd - r) * q) + idx;
}

// LDS bank-spread swizzle for packed variable-length rows (u32 elems)
__device__ static inline int swz32(int j) { return j + (j >> 5); }

// ---------------- block exclusive scan (all threads must call) ----------------
__device__ static inline uint32_t block_scan_excl(uint32_t v, uint32_t* lds) {
  int t = threadIdx.x;
  lds[t] = v;
  __syncthreads();
#pragma unroll
  for (int d = 1; d < THREADS; d <<= 1) {
    uint32_t add = (t >= d) ? lds[t - d] : 0u;
    __syncthreads();
    lds[t] += add;
    __syncthreads();
  }
  return lds[t] - v;
}

// single-block exclusive scan of src[0..n) -> dstart[0..n], dstart[n]=total;
// also copies the scan into gcur (runtime claim cursors).
__global__ void k_scan_small(const uint32_t* __restrict__ src, int n,
                             uint32_t* __restrict__ dstart, uint32_t* __restrict__ gcur) {
  __shared__ uint32_t lds[THREADS];
  int t = threadIdx.x;
  int K = (n + THREADS - 1) / THREADS;
  int s0 = t * K, s1 = (s0 + K < n) ? (s0 + K) : n;
  uint32_t s = 0;
  for (int j = s0; j < s1; ++j) s += src[j];
  lds[t] = s; __syncthreads();
#pragma unroll
  for (int dd = 1; dd < THREADS; dd <<= 1) {
    uint32_t a = (t >= dd) ? lds[t - dd] : 0u;
    __syncthreads();
    lds[t] += a;
    __syncthreads();
  }
  uint32_t run = lds[t] - s;
  for (int j = s0; j < s1; ++j) {
    uint32_t tmp = src[j];
    dstart[j] = run;
    gcur[j] = run;
    run += tmp;
  }
  if (t == THREADS - 1) dstart[n] = lds[THREADS - 1];
}

// in-place single-block exclusive scan (kept for output-phase bsums)
__global__ void k_scan_single(uint32_t* __restrict__ d, int n, uint32_t* __restrict__ total_out) {
  __shared__ uint32_t lds[THREADS];
  int t = threadIdx.x;
  int K = (n + THREADS - 1) / THREADS;
  int s0 = t * K, s1 = (s0 + K < n) ? (s0 + K) : n;
  uint32_t s = 0;
  for (int j = s0; j < s1; ++j) s += d[j];
  lds[t] = s; __syncthreads();
#pragma unroll
  for (int dd = 1; dd < THREADS; dd <<= 1) {
    uint32_t a = (t >= dd) ? lds[t - dd] : 0u;
    __syncthreads();
    lds[t] += a;
    __syncthreads();
  }
  uint32_t incl = lds[t];
  if (total_out && t == THREADS - 1) *total_out = incl;
  uint32_t run = incl - s;
  for (int j = s0; j < s1; ++j) { uint32_t tmp = d[j]; d[j] = run; run += tmp; }
}

// ---------------- edge pipeline: global hist + claim scatter + fused bucket sort ----------------
// one pass over row[]: LDS hist -> aggregated global atomics into eghist[4096]
__global__ void k_hist_glob(const int* __restrict__ row, int n, uint32_t* __restrict__ ghist) {
  __shared__ uint32_t h[EDIG];
  int b = blockIdx.x, t = threadIdx.x;
#pragma unroll
  for (int g = 0; g < EDIG / THREADS; ++g) h[g * THREADS + t] = 0;
  __syncthreads();
  int base = b * CHUNK;
  for (int j = t; j < CHUNK; j += THREADS) {
    int i = base + j;
    if (i < n) atomicAdd(&h[((uint32_t)row[i]) >> 8], 1u);
  }
  __syncthreads();
#pragma unroll
  for (int g = 0; g < EDIG / THREADS; ++g) {
    int d = g * THREADS + t;
    uint32_t c = h[d];
    if (c) atomicAdd(&ghist[d], c);
  }
}

// pack (row<<20|col), unstable scatter by row>>8; output ranges CLAIMED at runtime
// via one global atomicAdd per (block, present digit). No big hist, no offsets array.
__global__ __launch_bounds__(THREADS) void k_pack_scatter_claim(
    const int* __restrict__ row, const int* __restrict__ col,
    uint64_t* __restrict__ kout, uint32_t* __restrict__ gcur, int n) {
  constexpr int G = EDIG / THREADS;   // 16
  __shared__ uint64_t lkeys[CHUNK];   // 32 KB (first 1 KB doubles as scan temp)
  __shared__ uint32_t cur[EDIG];      // 16 KB: counts -> cursors -> wofs
  int b = xcd_swz(blockIdx.x, gridDim.x), t = threadIdx.x;
  int base = b * CHUNK;
#pragma unroll
  for (int g = 0; g < G; ++g) cur[g * THREADS + t] = 0;
  __syncthreads();
  uint64_t mykey[ITEMS];
#pragma unroll
  for (int batch = 0; batch < ITEMS; ++batch) {
    int i = base + batch * THREADS + t;
    uint64_t key = 0ull;
    if (i < n) {
      uint32_t r = (uint32_t)row[i];
      key = ((uint64_t)r << 20) | (uint32_t)col[i];
      atomicAdd(&cur[r >> 8], 1u);
    }
    mykey[batch] = key;
  }
  __syncthreads();
  uint32_t c[G], go[G], lstv[G];
  uint32_t s = 0;
#pragma unroll
  for (int g = 0; g < G; ++g) { c[g] = cur[G * t + g]; s += c[g]; }
  uint32_t tp = block_scan_excl(s, (uint32_t*)lkeys);
  __syncthreads();   // scan temp (lkeys) fully consumed before reuse
#pragma unroll
  for (int g = 0; g < G; ++g) {
    int d = G * t + g;
    lstv[g] = tp;
    cur[d] = tp;
    go[g] = c[g] ? atomicAdd(&gcur[d], c[g]) : 0u;   // claim output range
    tp += c[g];
  }
  __syncthreads();
#pragma unroll
  for (int batch = 0; batch < ITEMS; ++batch) {
    int i = base + batch * THREADS + t;
    if (i < n) {
      uint64_t key = mykey[batch];
      uint32_t dig = (uint32_t)(key >> 28);    // row>>8
      uint32_t slot = atomicAdd(&cur[dig], 1u);
      lkeys[slot] = key;
    }
  }
  __syncthreads();
#pragma unroll
  for (int g = 0; g < G; ++g) cur[G * t + g] = go[g] - lstv[g];  // wofs (u32 wrap-exact)
  __syncthreads();
  int nloc = n - base; if (nloc > CHUNK) nloc = CHUNK;
  for (int j = t; j < nloc; j += THREADS) {
    uint64_t key = lkeys[j];
    uint32_t dig = (uint32_t)(key >> 28);
    kout[cur[dig] + (uint32_t)j] = key;
  }
}

// one WG per 256-row bucket. u32-col sort with swizzled LDS addressing
// (R12 lesson: packed u64 rows hit bank 0 for every lane).
__global__ __launch_bounds__(THREADS) void k_bucket256(
    const uint64_t* __restrict__ U0, uint64_t* __restrict__ U1,
    const uint32_t* __restrict__ dstart, int E, int Nn, int* __restrict__ rowptr) {
  __shared__ uint32_t lbuf[BPHYS];    // ~19 KB swizzled cols (first 1 KB = scan temp)
  __shared__ uint8_t  rowof[BCAP];    // 4.5 KB row-id per slot
  __shared__ uint32_t cnt[BR];
  __shared__ uint32_t bs[BR + 1];
  int b = blockIdx.x, t = threadIdx.x;
  int s = (int)dstart[b];
  int e = (int)dstart[b + 1];
  int nseg = e - s;
  int r0 = b * BR;
  cnt[t] = 0;
  __syncthreads();
  for (int j = t; j < nseg; j += THREADS)
    atomicAdd(&cnt[(uint32_t)(U0[s + j] >> 20) & (BR - 1)], 1u);
  __syncthreads();
  uint32_t myc = cnt[t];
  uint32_t mybase = block_scan_excl(myc, lbuf);
  __syncthreads();   // scan temp fully consumed
  bs[t] = mybase;
  if (t == THREADS - 1) bs[BR] = mybase + myc;
  cnt[t] = mybase;   // cursor
  __syncthreads();
  if (nseg <= BCAP) {
    for (int j = t; j < nseg; j += THREADS) {
      uint64_t key = U0[s + j];   // L2-hot re-read
      uint32_t rl = (uint32_t)(key >> 20) & (BR - 1);
      uint32_t slot = atomicAdd(&cnt[rl], 1u);
      lbuf[swz32((int)slot)] = (uint32_t)(key & COLMASK);
      rowof[slot] = (uint8_t)rl;
    }
    __syncthreads();
    {  // insertion sort of row r0+t (u32 cols, swizzled addressing)
      int a0 = (int)bs[t], a1 = (int)bs[t + 1];
      for (int a = a0 + 1; a < a1; ++a) {
        uint32_t key = lbuf[swz32(a)];
        int p = a - 1;
        while (p >= a0 && lbuf[swz32(p)] > key) { lbuf[swz32(p + 1)] = lbuf[swz32(p)]; --p; }
        lbuf[swz32(p + 1)] = key;
      }
    }
    __syncthreads();
    for (int j = t; j < nseg; j += THREADS) {
      uint64_t key = ((uint64_t)(uint32_t)(r0 + rowof[j]) << 20) | lbuf[swz32(j)];
      U1[s + j] = key;
    }
  } else {
    // global fallback (statistically unreachable; correctness insurance)
    for (int j = t; j < nseg; j += THREADS) {
      uint64_t key = U0[s + j];
      uint32_t slot = atomicAdd(&cnt[(uint32_t)(key >> 20) & (BR - 1)], 1u);
      U1[s + slot] = key;
    }
    __syncthreads();
    int a0 = s + (int)bs[t], a1 = s + (int)bs[t + 1];
    for (int a = a0 + 1; a < a1; ++a) {
      uint64_t key = U1[a];
      int p = a - 1;
      while (p >= a0 && U1[p] > key) { U1[p + 1] = U1[p]; --p; }
      U1[p + 1] = key;
    }
  }
  int r = r0 + t;
  if (r < Nn) rowptr[r] = s + (int)bs[t];
  if (b == (int)gridDim.x - 1 && t == 0) rowptr[Nn] = E;
}

// ---------------- permutation: unique-key (bits<<20|i) MSD + per-bucket bitonic ----------------
__global__ void k_genkeys_glob(uint32_t ka, uint32_t kb, int n, uint64_t* __restrict__ K,
                               uint32_t* __restrict__ ghist) {
  __shared__ uint32_t h[PDIG];
  int b = blockIdx.x, t = threadIdx.x;
#pragma unroll
  for (int g = 0; g < PDIG / THREADS; ++g) h[g * THREADS + t] = 0;
  __syncthreads();
  int base = b * CHUNK;
  for (int j = t; j < CHUNK; j += THREADS) {
    int i = base + j;
    if (i < n) {
      uint32_t rb = rbits32(ka, kb, (uint32_t)i);
      K[i] = ((uint64_t)rb << 20) | (uint32_t)i;
      atomicAdd(&h[rb >> 22], 1u);   // top 10 bits
    }
  }
  __syncthreads();
#pragma unroll
  for (int g = 0; g < PDIG / THREADS; ++g) {
    int d = g * THREADS + t;
    uint32_t c = h[d];
    if (c) atomicAdd(&ghist[d], c);
  }
}

__global__ __launch_bounds__(THREADS) void k_scatter64p_claim(
    const uint64_t* __restrict__ kin, uint64_t* __restrict__ kout,
    uint32_t* __restrict__ gcur, int n) {
  constexpr int G = PDIG / THREADS;   // 4
  __shared__ uint64_t lkeys[CHUNK];   // 32 KB
  __shared__ uint32_t cur[PDIG];      // 4 KB
  int b = blockIdx.x, t = threadIdx.x;
  int base = b * CHUNK;
#pragma unroll
  for (int g = 0; g < G; ++g) cur[g * THREADS + t] = 0;
  __syncthreads();
  uint64_t mykey[ITEMS];
#pragma unroll
  for (int batch = 0; batch < ITEMS; ++batch) {
    int i = base + batch * THREADS + t;
    uint64_t key = 0ull;
    if (i < n) {
      key = kin[i];
      atomicAdd(&cur[(uint32_t)(key >> 42)], 1u);
    }
    mykey[batch] = key;
  }
  __syncthreads();
  uint32_t c[G], go[G], lstv[G];
  uint32_t s = 0;
#pragma unroll
  for (int g = 0; g < G; ++g) { c[g] = cur[G * t + g]; s += c[g]; }
  uint32_t tp = block_scan_excl(s, (uint32_t*)lkeys);
  __syncthreads();
#pragma unroll
  for (int g = 0; g < G; ++g) {
    int d = G * t + g;
    lstv[g] = tp;
    cur[d] = tp;
    go[g] = c[g] ? atomicAdd(&gcur[d], c[g]) : 0u;
    tp += c[g];
  }
  __syncthreads();
#pragma unroll
  for (int batch = 0; batch < ITEMS; ++batch) {
    int i = base + batch * THREADS + t;
    if (i < n) {
      uint64_t key = mykey[batch];
      uint32_t dig = (uint32_t)(key >> 42);
      uint32_t slot = atomicAdd(&cur[dig], 1u);
      lkeys[slot] = key;
    }
  }
  __syncthreads();
#pragma unroll
  for (int g = 0; g < G; ++g) cur[G * t + g] = go[g] - lstv[g];  // wofs
  __syncthreads();
  int nloc = n - base; if (nloc > CHUNK) nloc = CHUNK;
  for (int j = t; j < nloc; j += THREADS) {
    uint64_t key = lkeys[j];
    uint32_t dig = (uint32_t)(key >> 42);
    kout[cur[dig] + (uint32_t)j] = key;
  }
}

// per-bucket bitonic sort (2048-wide, padded with ~0). gsrc==null: out = low20 (perm1);
// else out = gsrc[low20] (round-2 payload gather).
__global__ __launch_bounds__(THREADS) void k_psort(
    const uint64_t* __restrict__ K, const uint32_t* __restrict__ dstart,
    uint32_t* __restrict__ outv, const uint32_t* __restrict__ gsrc) {
  __shared__ uint64_t sb[2048];   // 16 KB
  int b = blockIdx.x, t = threadIdx.x;
  int s = (int)dstart[b], e = (int)dstart[b + 1];
  int nseg = e - s;   // avg 977, sigma 31; 2048 = +34 sigma
  for (int j = t; j < 2048; j += THREADS)
    sb[j] = (j < nseg) ? K[s + j] : ~0ull;
  __syncthreads();
  for (int k = 2; k <= 2048; k <<= 1) {
    for (int j = k >> 1; j > 0; j >>= 1) {
      for (int i = t; i < 2048; i += THREADS) {
        int l = i ^ j;
        if (l > i) {
          bool up = ((i & k) == 0);
          uint64_t a = sb[i], c = sb[l];
          if ((a > c) == up) { sb[i] = c; sb[l] = a; }
        }
      }
      __syncthreads();
    }
  }
  for (int j = t; j < nseg; j += THREADS) {
    uint32_t p = (uint32_t)(sb[j] & COLMASK);
    outv[s + j] = gsrc ? gsrc[p] : p;
  }
}

// ---------------- random walks ----------------
__global__ void k_walk(const int* __restrict__ start, int S,
                       const int* __restrict__ rowptr, const uint64_t* __restrict__ U,
                       uint8_t* __restrict__ hits,
                       uint32_t k0a, uint32_t k0b, uint32_t k1a, uint32_t k1b,
                       uint32_t k2a, uint32_t k2b) {
  int i = blockIdx.x * blockDim.x + threadIdx.x;
  int st = gridDim.x * blockDim.x;
  for (; i < S; i += st) {
    int cur = start[i];
    bool active = true;
    uint32_t ka[3] = {k0a, k1a, k2a};
    uint32_t kb[3] = {k0b, k1b, k2b};
#pragma unroll
    for (int s = 0; s < 3; ++s) {
      int rp = rowptr[cur];
      int d = rowptr[cur + 1] - rp;
      bool act = active && (d > 0);
      if (act) hits[cur] = 1;
      uint32_t bits = rbits32(ka[s], kb[s], (uint32_t)i);
      float u = __uint_as_float((bits >> 9) | 0x3f800000u) - 1.0f;  // jax uniform [0,1)
      int off = (int)floorf(u * (float)d);
      int dm1 = d - 1; if (dm1 < 0) dm1 = 0;
      if (off > dm1) off = dm1;
      if (act) cur = (int)(U[rp + off] & COLMASK);
      active = act;
    }
  }
}

// ---------------- outputs (masked edges only exist at i < Nn) ----------------
__global__ void k_mask_copy(const uint8_t* __restrict__ hits, const uint64_t* __restrict__ U,
                            int Nn, uint32_t* __restrict__ bsums, uint64_t* __restrict__ hstage) {
  __shared__ uint32_t lds[THREADS];
  int b = blockIdx.x, t = threadIdx.x;
  int base = b * CHUNK + t * ITEMS;
  uint32_t s = 0;
#pragma unroll
  for (int j = 0; j < ITEMS; ++j) {
    int i = base + j;
    if (i < Nn) { s += (uint32_t)(!hits[i]); hstage[i] = U[i]; }
  }
  lds[t] = s; __syncthreads();
  for (int d2 = THREADS / 2; d2 > 0; d2 >>= 1) { if (t < d2) lds[t] += lds[t + d2]; __syncthreads(); }
  if (t == 0) bsums[b] = lds[0];
}

__global__ void k_out_tail(const uint64_t* __restrict__ U, int E, int Nn,
                           const uint32_t* __restrict__ keephead,
                           int* __restrict__ A, int* __restrict__ B, int* __restrict__ M) {
  int nm = Nn - (int)*keephead;
  int i = Nn + blockIdx.x * blockDim.x + threadIdx.x;
  int st = gridDim.x * blockDim.x;
  for (; i < E; i += st) {
    uint64_t key = U[i];
    A[i - nm] = (int)(key >> 20);
    B[i - nm] = (int)(key & COLMASK);
    M[i] = 1;
  }
}

__global__ void k_out_headCD(const uint64_t* __restrict__ hstage, const uint8_t* __restrict__ hits,
                             int Nn, const uint32_t* __restrict__ bsums,
                             int* __restrict__ A, int* __restrict__ B,
                             int* __restrict__ C, int* __restrict__ D, int* __restrict__ M) {
  __shared__ uint32_t lds[THREADS];
  int b = blockIdx.x, t = threadIdx.x;
  int base = b * CHUNK + t * ITEMS;
  uint32_t keep[ITEMS]; uint32_t s = 0;
#pragma unroll
  for (int j = 0; j < ITEMS; ++j) {
    int i = base + j;
    uint32_t k = (i < Nn) ? (uint32_t)(!hits[i]) : 0u;
    keep[j] = k; s += k;
  }
  uint32_t kr = bsums[b] + block_scan_excl(s, lds);
#pragma unroll
  for (int j = 0; j < ITEMS; ++j) {
    int i = base + j;
    if (i < Nn) {
      uint64_t key = hstage[i];
      if (keep[j]) { A[kr] = (int)(key >> 20); B[kr] = (int)(key & COLMASK); M[i] = 1; ++kr; }
      else { uint32_t mr = (uint32_t)i - kr; C[mr] = (int)(key >> 20); D[mr] = (int)(key & COLMASK); M[i] = 0; }
    }
  }
}

__global__ void k_cdfill(int E, int Nn, const uint32_t* __restrict__ keephead,
                         int* __restrict__ A, int* __restrict__ B,
                         int* __restrict__ C, int* __restrict__ D) {
  int nm = Nn - (int)*keephead;
  int j = blockIdx.x * blockDim.x + threadIdx.x;
  int st = gridDim.x * blockDim.x;
  for (; j < E; j += st) {
    if (j >= nm) { C[j] = -1; D[j] = -1; }
    if (j >= E - nm) { A[j] = -1; B[j] = -1; }
  }
}

// ---------------- launcher ----------------
extern "C" void kernel_launch(void* const* d_in, const int* in_sizes, int n_in,
                              void* d_out, int out_size, void* d_ws, size_t ws_size,
                              hipStream_t stream) {
  const int E = in_sizes[0] / 2;
  const int Nn = 1000000;   // num_nodes (fixed problem)
  const int S = 700000;     // round(0.7*N) * WALKS_PER_NODE
  const int NB_N = (Nn + CHUNK - 1) / CHUNK;      // 245
  const int NB_E = (E + CHUNK - 1) / CHUNK;       // 3907
  const int NBUCK = (Nn + BR - 1) / BR;           // 3907 edge buckets
  const int NB_P = (Nn + CHUNK - 1) / CHUNK;      // 245 perm blocks

  const int* row = (const int*)d_in[0];
  const int* col = row + (size_t)E;

  int* out = (int*)d_out;
  int* A = out;                      // final: remaining rows
  int* B = out + (size_t)E;          // final: remaining cols
  int* C = out + (size_t)2 * E;      // final: masked rows
  int* D = out + (size_t)3 * E;      // final: masked cols
  int* M = out + (size_t)4 * E;      // final: edge_mask; staging: perm bufs + hist/cursors
  uint64_t* U0 = (uint64_t*)out;                    // spans A+B (128MB)
  uint64_t* U1 = (uint64_t*)(out + (size_t)2 * E);  // spans C+D (128MB)

  // workspace carve (same proven budget)
  char* w = (char*)d_ws;
  uint64_t* hstage = (uint64_t*)w;            // 8,000,000 B (output phase only)
  int* rowptr = (int*)w;                      // 4,000,004 B (aliases hstage; dead after walk)
  w += (size_t)Nn * 8;
  uint8_t* hits = (uint8_t*)w; w += Nn;       // 1,000,000 B
  w = (char*)(((uintptr_t)w + 255) & ~(uintptr_t)255);
  uint32_t* bsums = (uint32_t*)w; w += (size_t)4096 * 4;
  uint32_t* scal = (uint32_t*)w;  w += 64;
  if ((size_t)(w - (char*)d_ws) > ws_size) return;  // insufficient scratch: fail visibly

  // staging inside M region (64 MB), all dead before M written in output phase:
  uint64_t* K64a  = (uint64_t*)M;                       // [0,  8MB)
  uint64_t* K64b  = (uint64_t*)(M + (size_t)2 * Nn);    // [8, 16MB)
  uint32_t* perm1 = (uint32_t*)(M + (size_t)4 * Nn);    // [16,20MB)
  uint32_t* startv= (uint32_t*)(M + (size_t)5 * Nn);    // [20,24MB)
  uint32_t* aux   = (uint32_t*)(M + (size_t)6 * Nn);    // [24MB+): small arrays
  uint32_t* eghist  = aux;            // 4096
  uint32_t* edstart = aux + 4096;     // 4097
  uint32_t* egcur   = aux + 8704;     // 4096
  uint32_t* pghist  = aux + 12800;    // 1024
  uint32_t* pdstart = aux + 13824;    // 1025
  uint32_t* pgcur   = aux + 14976;    // 1024

  // ---- host-side key derivation (JAX threefry, partitionable split = fold_in) ----
  struct KK { uint32_t a, b; };
  auto fold = [](KK k, uint32_t j) { KK r; tf2x32(k.a, k.b, 0u, j, &r.a, &r.b); return r; };
  KK base{0u, 42u};
  KK kperm = fold(base, 0u);
  KK kwalk = fold(base, 1u);
  KK keyA  = fold(kperm, 0u);
  KK sub1  = fold(kperm, 1u);
  KK sub2  = fold(keyA, 1u);
  KK wk0 = fold(kwalk, 0u), wk1 = fold(kwalk, 1u), wk2 = fold(kwalk, 2u);

  hipMemsetAsync(hits, 0, (size_t)Nn, stream);
  hipMemsetAsync(eghist, 0, (size_t)EDIG * 4, stream);

  // ---- 1) edge sort: global hist -> tiny scan -> claim scatter -> bucket sort ----
  k_hist_glob<<<NB_E, THREADS, 0, stream>>>(row, E, eghist);
  k_scan_small<<<1, THREADS, 0, stream>>>(eghist, EDIG, edstart, egcur);
  k_pack_scatter_claim<<<NB_E, THREADS, 0, stream>>>(row, col, U0, egcur, E);
  k_bucket256<<<NBUCK, THREADS, 0, stream>>>(U0, U1, edstart, E, Nn, rowptr);

  // ---- 2) permutation: 2 rounds of unique-key MSD + bitonic bucket sort ----
  hipMemsetAsync(pghist, 0, (size_t)PDIG * 4, stream);
  k_genkeys_glob<<<NB_P, THREADS, 0, stream>>>(sub1.a, sub1.b, Nn, K64a, pghist);
  k_scan_small<<<1, THREADS, 0, stream>>>(pghist, PDIG, pdstart, pgcur);
  k_scatter64p_claim<<<NB_P, THREADS, 0, stream>>>(K64a, K64b, pgcur, Nn);
  k_psort<<<PDIG, THREADS, 0, stream>>>(K64b, pdstart, perm1, (const uint32_t*)nullptr);
  hipMemsetAsync(pghist, 0, (size_t)PDIG * 4, stream);
  k_genkeys_glob<<<NB_P, THREADS, 0, stream>>>(sub2.a, sub2.b, Nn, K64a, pghist);
  k_scan_small<<<1, THREADS, 0, stream>>>(pghist, PDIG, pdstart, pgcur);
  k_scatter64p_claim<<<NB_P, THREADS, 0, stream>>>(K64a, K64b, pgcur, Nn);
  k_psort<<<PDIG, THREADS, 0, stream>>>(K64b, pdstart, startv, perm1);

  // ---- 3) random walks: mark hit nodes ----
  k_walk<<<(S + THREADS - 1) / THREADS, THREADS, 0, stream>>>(
      (const int*)startv, S, rowptr, U1, hits, wk0.a, wk0.b, wk1.a, wk1.b, wk2.a, wk2.b);

  // ---- 4) outputs: copy head + keep-scan, tail shift, head compaction, -1 fills ----
  k_mask_copy<<<NB_N, THREADS, 0, stream>>>(hits, U1, Nn, bsums, hstage);
  k_scan_single<<<1, THREADS, 0, stream>>>(bsums, NB_N, &scal[0]);   // scal[0] = keeps among i<Nn
  k_out_tail<<<4096, THREADS, 0, stream>>>(U1, E, Nn, &scal[0], A, B, M);
  k_out_headCD<<<NB_N, THREADS, 0, stream>>>(hstage, hits, Nn, bsums, A, B, C, D, M);
  k_cdfill<<<4096, THREADS, 0, stream>>>(E, Nn, &scal[0], A, B, C, D);
}

// Round 15
// 1051.065 us; speedup vs baseline: 1.4567x; 1.4567x over previous
//
#include <hip/hip_runtime.h>
#include <stdint.h>

#define THREADS 256
#define ITEMS 16
#define CHUNK (THREADS * ITEMS)
#define COLMASK 0xFFFFFu
#define EDIG 4096      // edge scatter digits = row>>8
#define BR 256         // rows per edge bucket
#define BCAP 4608      // bucket capacity (avg 4096, +8 sigma)
#define BPHYS (BCAP + (BCAP >> 5) + 8)   // swizzled u32 capacity
#define PDIG 1024      // perm MSD digits

// ---------------- threefry2x32, JAX-compatible (20 rounds) ----------------
__host__ __device__ static inline void tf2x32(uint32_t k0, uint32_t k1,
                                              uint32_t x0, uint32_t x1,
                                              uint32_t* o0, uint32_t* o1) {
  uint32_t ks[3] = {k0, k1, k0 ^ k1 ^ 0x1BD11BDAu};
  x0 += ks[0]; x1 += ks[1];
  const uint32_t RA[4] = {13u, 15u, 26u, 6u};
  const uint32_t RB[4] = {17u, 29u, 16u, 24u};
#pragma unroll
  for (int g = 0; g < 5; ++g) {
    const uint32_t* R = (g & 1) ? RB : RA;
#pragma unroll
    for (int j = 0; j < 4; ++j) {
      x0 += x1;
      x1 = (x1 << R[j]) | (x1 >> (32u - R[j]));
      x1 ^= x0;
    }
    x0 += ks[(g + 1) % 3];
    x1 += ks[(g + 2) % 3] + (uint32_t)(g + 1);
  }
  *o0 = x0; *o1 = x1;
}

__device__ static inline uint32_t rbits32(uint32_t ka, uint32_t kb, uint32_t i) {
  uint32_t o0, o1;
  tf2x32(ka, kb, 0u, i, &o0, &o1);
  return o0 ^ o1;
}

// bijective XCD-aware block swizzle (m204 variant; works for any nwg)
__device__ static inline int xcd_swz(int orig, int nwg) {
  int q = nwg >> 3, r = nwg & 7;
  int xcd = orig & 7, idx = orig >> 3;
  return (xcd < r ? xcd * (q + 1) : r * (q + 1) + (xcd - r) * q) + idx;
}

// LDS bank-spread swizzle for packed variable-length rows (u32 elems)
__device__ static inline int swz32(int j) { return j + (j >> 5); }

// ---------------- block exclusive scan (all threads must call) ----------------
__device__ static inline uint32_t block_scan_excl(uint32_t v, uint32_t* lds) {
  int t = threadIdx.x;
  lds[t] = v;
  __syncthreads();
#pragma unroll
  for (int d = 1; d < THREADS; d <<= 1) {
    uint32_t add = (t >= d) ? lds[t - d] : 0u;
    __syncthreads();
    lds[t] += add;
    __syncthreads();
  }
  return lds[t] - v;
}

// ---------------- hierarchical scan helpers ----------------
__global__ void k_sums_u32(const uint32_t* __restrict__ d, int n, uint32_t* __restrict__ bsums) {
  __shared__ uint32_t lds[THREADS];
  int b = blockIdx.x, t = threadIdx.x;
  int base = b * CHUNK + t * ITEMS;
  uint32_t s = 0;
#pragma unroll
  for (int j = 0; j < ITEMS; ++j) { int i = base + j; if (i < n) s += d[i]; }
  lds[t] = s; __syncthreads();
  for (int d2 = THREADS / 2; d2 > 0; d2 >>= 1) { if (t < d2) lds[t] += lds[t + d2]; __syncthreads(); }
  if (t == 0) bsums[b] = lds[0];
}

__global__ void k_scan_single(uint32_t* __restrict__ d, int n, uint32_t* __restrict__ total_out) {
  __shared__ uint32_t lds[THREADS];
  int t = threadIdx.x;
  int K = (n + THREADS - 1) / THREADS;
  int s0 = t * K, s1 = (s0 + K < n) ? (s0 + K) : n;
  uint32_t s = 0;
  for (int j = s0; j < s1; ++j) s += d[j];
  lds[t] = s; __syncthreads();
#pragma unroll
  for (int dd = 1; dd < THREADS; dd <<= 1) {
    uint32_t a = (t >= dd) ? lds[t - dd] : 0u;
    __syncthreads();
    lds[t] += a;
    __syncthreads();
  }
  uint32_t incl = lds[t];
  if (total_out && t == THREADS - 1) *total_out = incl;
  uint32_t run = incl - s;
  for (int j = s0; j < s1; ++j) { uint32_t tmp = d[j]; d[j] = run; run += tmp; }
}

__global__ void k_excl_u32(uint32_t* __restrict__ d, int n, const uint32_t* __restrict__ bsums) {
  __shared__ uint32_t lds[THREADS];
  int b = blockIdx.x, t = threadIdx.x;
  int base = b * CHUNK + t * ITEMS;
  uint32_t v[ITEMS]; uint32_t s = 0;
#pragma unroll
  for (int j = 0; j < ITEMS; ++j) { int i = base + j; uint32_t x = (i < n) ? d[i] : 0u; v[j] = x; s += x; }
  uint32_t run = bsums[b] + block_scan_excl(s, lds);
#pragma unroll
  for (int j = 0; j < ITEMS; ++j) { int i = base + j; if (i < n) d[i] = run; run += v[j]; }
}

// capture per-digit global starts (hist[d*NB] after scan)
__global__ void k_dig_starts(const uint32_t* __restrict__ hist, int NB, int DIG, int total,
                             uint32_t* __restrict__ dstart) {
  int d = blockIdx.x * blockDim.x + threadIdx.x;
  if (d < DIG) dstart[d] = hist[(size_t)d * NB];
  else if (d == DIG) dstart[DIG] = (uint32_t)total;
}

// ---------------- edge pipeline: 1 unstable 12-bit pass + fused bucket sort ----------------
// R14 lesson: runtime atomic claims on 4096 words = 16M contended atomics (798us).
// R13 lesson: UNSWIZZLED hist writes put the 16 columns of each 64B line on 8
// different XCD L2s -> ~8x write-back amplification (687 MB). Fix: same xcd_swz
// as the scatter, so adjacent hist columns are written by same-XCD blocks.
__global__ void k_hist12(const int* __restrict__ row, int n, int NB, uint32_t* __restrict__ hist) {
  __shared__ uint32_t h[EDIG];
  int b = xcd_swz(blockIdx.x, gridDim.x), t = threadIdx.x;
#pragma unroll
  for (int g = 0; g < EDIG / THREADS; ++g) h[g * THREADS + t] = 0;
  __syncthreads();
  int base = b * CHUNK;
  for (int j = t; j < CHUNK; j += THREADS) {
    int i = base + j;
    if (i < n) atomicAdd(&h[((uint32_t)row[i]) >> 8], 1u);
  }
  __syncthreads();
#pragma unroll
  for (int g = 0; g < EDIG / THREADS; ++g) {
    int d = g * THREADS + t;
    hist[(size_t)d * NB + b] = h[d];
  }
}

// pack (row<<20|col), unstable scatter by row>>8. gofs/lst in registers;
// cur[] reused as wofs behind a barrier (R12 lesson: no global reads in hot loop).
__global__ __launch_bounds__(THREADS) void k_pack_scatter12(
    const int* __restrict__ row, const int* __restrict__ col,
    uint64_t* __restrict__ kout, const uint32_t* __restrict__ hist, int n, int NB) {
  constexpr int G = EDIG / THREADS;   // 16
  __shared__ uint64_t lkeys[CHUNK];   // 32 KB (first 1 KB doubles as scan temp)
  __shared__ uint32_t cur[EDIG];      // 16 KB: counts -> cursors -> wofs
  int b = xcd_swz(blockIdx.x, gridDim.x), t = threadIdx.x;
  int base = b * CHUNK;
#pragma unroll
  for (int g = 0; g < G; ++g) cur[g * THREADS + t] = 0;
  __syncthreads();
  uint64_t mykey[ITEMS];
#pragma unroll
  for (int batch = 0; batch < ITEMS; ++batch) {
    int i = base + batch * THREADS + t;
    uint64_t key = 0ull;
    if (i < n) {
      uint32_t r = (uint32_t)row[i];
      key = ((uint64_t)r << 20) | (uint32_t)col[i];
      atomicAdd(&cur[r >> 8], 1u);
    }
    mykey[batch] = key;
  }
  __syncthreads();
  uint32_t c[G], go[G], lstv[G];
  uint32_t s = 0;
#pragma unroll
  for (int g = 0; g < G; ++g) { c[g] = cur[G * t + g]; s += c[g]; }
  uint32_t tp = block_scan_excl(s, (uint32_t*)lkeys);
  __syncthreads();   // scan temp (lkeys) fully consumed before reuse
#pragma unroll
  for (int g = 0; g < G; ++g) {
    int d = G * t + g;
    go[g] = hist[(size_t)d * NB + b];   // single strided read; L2-shared across blocks
    lstv[g] = tp;
    cur[d] = tp;
    tp += c[g];
  }
  __syncthreads();
#pragma unroll
  for (int batch = 0; batch < ITEMS; ++batch) {
    int i = base + batch * THREADS + t;
    if (i < n) {
      uint64_t key = mykey[batch];
      uint32_t dig = (uint32_t)(key >> 28);    // row>>8
      uint32_t slot = atomicAdd(&cur[dig], 1u);
      lkeys[slot] = key;
    }
  }
  __syncthreads();
#pragma unroll
  for (int g = 0; g < G; ++g) cur[G * t + g] = go[g] - lstv[g];  // wofs (u32 wrap-exact)
  __syncthreads();
  int nloc = n - base; if (nloc > CHUNK) nloc = CHUNK;
  for (int j = t; j < nloc; j += THREADS) {
    uint64_t key = lkeys[j];
    uint32_t dig = (uint32_t)(key >> 28);
    kout[cur[dig] + (uint32_t)j] = key;
  }
}

// one WG per 256-row bucket. u32-col sort with swizzled LDS addressing
// (R12 lesson: packed u64 rows hit bank 0 for every lane).
__global__ __launch_bounds__(THREADS) void k_bucket256(
    const uint64_t* __restrict__ U0, uint64_t* __restrict__ U1,
    const uint32_t* __restrict__ dstart, int E, int Nn, int* __restrict__ rowptr) {
  __shared__ uint32_t lbuf[BPHYS];    // ~19 KB swizzled cols (first 1 KB = scan temp)
  __shared__ uint8_t  rowof[BCAP];    // 4.5 KB row-id per slot
  __shared__ uint32_t cnt[BR];
  __shared__ uint32_t bs[BR + 1];
  int b = blockIdx.x, t = threadIdx.x;
  int s = (int)dstart[b];
  int e = (int)dstart[b + 1];
  int nseg = e - s;
  int r0 = b * BR;
  cnt[t] = 0;
  __syncthreads();
  for (int j = t; j < nseg; j += THREADS)
    atomicAdd(&cnt[(uint32_t)(U0[s + j] >> 20) & (BR - 1)], 1u);
  __syncthreads();
  uint32_t myc = cnt[t];
  uint32_t mybase = block_scan_excl(myc, lbuf);
  __syncthreads();   // scan temp fully consumed
  bs[t] = mybase;
  if (t == THREADS - 1) bs[BR] = mybase + myc;
  cnt[t] = mybase;   // cursor
  __syncthreads();
  if (nseg <= BCAP) {
    for (int j = t; j < nseg; j += THREADS) {
      uint64_t key = U0[s + j];   // L2-hot re-read
      uint32_t rl = (uint32_t)(key >> 20) & (BR - 1);
      uint32_t slot = atomicAdd(&cnt[rl], 1u);
      lbuf[swz32((int)slot)] = (uint32_t)(key & COLMASK);
      rowof[slot] = (uint8_t)rl;
    }
    __syncthreads();
    {  // insertion sort of row r0+t (u32 cols, swizzled addressing)
      int a0 = (int)bs[t], a1 = (int)bs[t + 1];
      for (int a = a0 + 1; a < a1; ++a) {
        uint32_t key = lbuf[swz32(a)];
        int p = a - 1;
        while (p >= a0 && lbuf[swz32(p)] > key) { lbuf[swz32(p + 1)] = lbuf[swz32(p)]; --p; }
        lbuf[swz32(p + 1)] = key;
      }
    }
    __syncthreads();
    for (int j = t; j < nseg; j += THREADS) {
      uint64_t key = ((uint64_t)(uint32_t)(r0 + rowof[j]) << 20) | lbuf[swz32(j)];
      U1[s + j] = key;
    }
  } else {
    // global fallback (statistically unreachable; correctness insurance)
    for (int j = t; j < nseg; j += THREADS) {
      uint64_t key = U0[s + j];
      uint32_t slot = atomicAdd(&cnt[(uint32_t)(key >> 20) & (BR - 1)], 1u);
      U1[s + slot] = key;
    }
    __syncthreads();
    int a0 = s + (int)bs[t], a1 = s + (int)bs[t + 1];
    for (int a = a0 + 1; a < a1; ++a) {
      uint64_t key = U1[a];
      int p = a - 1;
      while (p >= a0 && U1[p] > key) { U1[p + 1] = U1[p]; --p; }
      U1[p + 1] = key;
    }
  }
  int r = r0 + t;
  if (r < Nn) rowptr[r] = s + (int)bs[t];
  if (b == (int)gridDim.x - 1 && t == 0) rowptr[Nn] = E;
}

// ---------------- permutation: unique-key (bits<<20|i) MSD + per-bucket bitonic ----------------
__global__ void k_genkeys64(uint32_t ka, uint32_t kb, int n, uint64_t* __restrict__ K,
                            int NB, uint32_t* __restrict__ hist) {
  __shared__ uint32_t h[PDIG];
  int b = blockIdx.x, t = threadIdx.x;
#pragma unroll
  for (int g = 0; g < PDIG / THREADS; ++g) h[g * THREADS + t] = 0;
  __syncthreads();
  int base = b * CHUNK;
  for (int j = t; j < CHUNK; j += THREADS) {
    int i = base + j;
    if (i < n) {
      uint32_t rb = rbits32(ka, kb, (uint32_t)i);
      K[i] = ((uint64_t)rb << 20) | (uint32_t)i;
      atomicAdd(&h[rb >> 22], 1u);   // top 10 bits
    }
  }
  __syncthreads();
#pragma unroll
  for (int g = 0; g < PDIG / THREADS; ++g) {
    int d = g * THREADS + t;
    hist[(size_t)d * NB + b] = h[d];
  }
}

__global__ __launch_bounds__(THREADS) void k_scatter64p(
    const uint64_t* __restrict__ kin, uint64_t* __restrict__ kout,
    const uint32_t* __restrict__ hist, int n, int NB) {
  constexpr int G = PDIG / THREADS;   // 4
  __shared__ uint64_t lkeys[CHUNK];   // 32 KB
  __shared__ uint32_t cur[PDIG];      // 4 KB
  int b = blockIdx.x, t = threadIdx.x;
  int base = b * CHUNK;
#pragma unroll
  for (int g = 0; g < G; ++g) cur[g * THREADS + t] = 0;
  __syncthreads();
  uint64_t mykey[ITEMS];
#pragma unroll
  for (int batch = 0; batch < ITEMS; ++batch) {
    int i = base + batch * THREADS + t;
    uint64_t key = 0ull;
    if (i < n) {
      key = kin[i];
      atomicAdd(&cur[(uint32_t)(key >> 42)], 1u);
    }
    mykey[batch] = key;
  }
  __syncthreads();
  uint32_t c[G], go[G], lstv[G];
  uint32_t s = 0;
#pragma unroll
  for (int g = 0; g < G; ++g) { c[g] = cur[G * t + g]; s += c[g]; }
  uint32_t tp = block_scan_excl(s, (uint32_t*)lkeys);
  __syncthreads();
#pragma unroll
  for (int g = 0; g < G; ++g) {
    int d = G * t + g;
    go[g] = hist[(size_t)d * NB + b];
    lstv[g] = tp;
    cur[d] = tp;
    tp += c[g];
  }
  __syncthreads();
#pragma unroll
  for (int batch = 0; batch < ITEMS; ++batch) {
    int i = base + batch * THREADS + t;
    if (i < n) {
      uint64_t key = mykey[batch];
      uint32_t dig = (uint32_t)(key >> 42);
      uint32_t slot = atomicAdd(&cur[dig], 1u);
      lkeys[slot] = key;
    }
  }
  __syncthreads();
#pragma unroll
  for (int g = 0; g < G; ++g) cur[G * t + g] = go[g] - lstv[g];  // wofs
  __syncthreads();
  int nloc = n - base; if (nloc > CHUNK) nloc = CHUNK;
  for (int j = t; j < nloc; j += THREADS) {
    uint64_t key = lkeys[j];
    uint32_t dig = (uint32_t)(key >> 42);
    kout[cur[dig] + (uint32_t)j] = key;
  }
}

// per-bucket bitonic sort (2048-wide, padded with ~0). gsrc==null: out = low20 (perm1);
// else out = gsrc[low20] (round-2 payload gather).
__global__ __launch_bounds__(THREADS) void k_psort(
    const uint64_t* __restrict__ K, const uint32_t* __restrict__ dstart,
    uint32_t* __restrict__ outv, const uint32_t* __restrict__ gsrc) {
  __shared__ uint64_t sb[2048];   // 16 KB
  int b = blockIdx.x, t = threadIdx.x;
  int s = (int)dstart[b], e = (int)dstart[b + 1];
  int nseg = e - s;   // avg 977, sigma 31; 2048 = +34 sigma
  for (int j = t; j < 2048; j += THREADS)
    sb[j] = (j < nseg) ? K[s + j] : ~0ull;
  __syncthreads();
  for (int k = 2; k <= 2048; k <<= 1) {
    for (int j = k >> 1; j > 0; j >>= 1) {
      for (int i = t; i < 2048; i += THREADS) {
        int l = i ^ j;
        if (l > i) {
          bool up = ((i & k) == 0);
          uint64_t a = sb[i], c = sb[l];
          if ((a > c) == up) { sb[i] = c; sb[l] = a; }
        }
      }
      __syncthreads();
    }
  }
  for (int j = t; j < nseg; j += THREADS) {
    uint32_t p = (uint32_t)(sb[j] & COLMASK);
    outv[s + j] = gsrc ? gsrc[p] : p;
  }
}

// ---------------- random walks ----------------
__global__ void k_walk(const int* __restrict__ start, int S,
                       const int* __restrict__ rowptr, const uint64_t* __restrict__ U,
                       uint8_t* __restrict__ hits,
                       uint32_t k0a, uint32_t k0b, uint32_t k1a, uint32_t k1b,
                       uint32_t k2a, uint32_t k2b) {
  int i = blockIdx.x * blockDim.x + threadIdx.x;
  int st = gridDim.x * blockDim.x;
  for (; i < S; i += st) {
    int cur = start[i];
    bool active = true;
    uint32_t ka[3] = {k0a, k1a, k2a};
    uint32_t kb[3] = {k0b, k1b, k2b};
#pragma unroll
    for (int s = 0; s < 3; ++s) {
      int rp = rowptr[cur];
      int d = rowptr[cur + 1] - rp;
      bool act = active && (d > 0);
      if (act) hits[cur] = 1;
      uint32_t bits = rbits32(ka[s], kb[s], (uint32_t)i);
      float u = __uint_as_float((bits >> 9) | 0x3f800000u) - 1.0f;  // jax uniform [0,1)
      int off = (int)floorf(u * (float)d);
      int dm1 = d - 1; if (dm1 < 0) dm1 = 0;
      if (off > dm1) off = dm1;
      if (act) cur = (int)(U[rp + off] & COLMASK);
      active = act;
    }
  }
}

// ---------------- outputs (masked edges only exist at i < Nn) ----------------
__global__ void k_mask_copy(const uint8_t* __restrict__ hits, const uint64_t* __restrict__ U,
                            int Nn, uint32_t* __restrict__ bsums, uint64_t* __restrict__ hstage) {
  __shared__ uint32_t lds[THREADS];
  int b = blockIdx.x, t = threadIdx.x;
  int base = b * CHUNK + t * ITEMS;
  uint32_t s = 0;
#pragma unroll
  for (int j = 0; j < ITEMS; ++j) {
    int i = base + j;
    if (i < Nn) { s += (uint32_t)(!hits[i]); hstage[i] = U[i]; }
  }
  lds[t] = s; __syncthreads();
  for (int d2 = THREADS / 2; d2 > 0; d2 >>= 1) { if (t < d2) lds[t] += lds[t + d2]; __syncthreads(); }
  if (t == 0) bsums[b] = lds[0];
}

__global__ void k_out_tail(const uint64_t* __restrict__ U, int E, int Nn,
                           const uint32_t* __restrict__ keephead,
                           int* __restrict__ A, int* __restrict__ B, int* __restrict__ M) {
  int nm = Nn - (int)*keephead;
  int i = Nn + blockIdx.x * blockDim.x + threadIdx.x;
  int st = gridDim.x * blockDim.x;
  for (; i < E; i += st) {
    uint64_t key = U[i];
    A[i - nm] = (int)(key >> 20);
    B[i - nm] = (int)(key & COLMASK);
    M[i] = 1;
  }
}

__global__ void k_out_headCD(const uint64_t* __restrict__ hstage, const uint8_t* __restrict__ hits,
                             int Nn, const uint32_t* __restrict__ bsums,
                             int* __restrict__ A, int* __restrict__ B,
                             int* __restrict__ C, int* __restrict__ D, int* __restrict__ M) {
  __shared__ uint32_t lds[THREADS];
  int b = blockIdx.x, t = threadIdx.x;
  int base = b * CHUNK + t * ITEMS;
  uint32_t keep[ITEMS]; uint32_t s = 0;
#pragma unroll
  for (int j = 0; j < ITEMS; ++j) {
    int i = base + j;
    uint32_t k = (i < Nn) ? (uint32_t)(!hits[i]) : 0u;
    keep[j] = k; s += k;
  }
  uint32_t kr = bsums[b] + block_scan_excl(s, lds);
#pragma unroll
  for (int j = 0; j < ITEMS; ++j) {
    int i = base + j;
    if (i < Nn) {
      uint64_t key = hstage[i];
      if (keep[j]) { A[kr] = (int)(key >> 20); B[kr] = (int)(key & COLMASK); M[i] = 1; ++kr; }
      else { uint32_t mr = (uint32_t)i - kr; C[mr] = (int)(key >> 20); D[mr] = (int)(key & COLMASK); M[i] = 0; }
    }
  }
}

__global__ void k_cdfill(int E, int Nn, const uint32_t* __restrict__ keephead,
                         int* __restrict__ A, int* __restrict__ B,
                         int* __restrict__ C, int* __restrict__ D) {
  int nm = Nn - (int)*keephead;
  int j = blockIdx.x * blockDim.x + threadIdx.x;
  int st = gridDim.x * blockDim.x;
  for (; j < E; j += st) {
    if (j >= nm) { C[j] = -1; D[j] = -1; }
    if (j >= E - nm) { A[j] = -1; B[j] = -1; }
  }
}

// ---------------- launcher ----------------
extern "C" void kernel_launch(void* const* d_in, const int* in_sizes, int n_in,
                              void* d_out, int out_size, void* d_ws, size_t ws_size,
                              hipStream_t stream) {
  const int E = in_sizes[0] / 2;
  const int Nn = 1000000;   // num_nodes (fixed problem)
  const int S = 700000;     // round(0.7*N) * WALKS_PER_NODE
  const int NB_N = (Nn + CHUNK - 1) / CHUNK;      // 245
  const int NB_E = (E + CHUNK - 1) / CHUNK;       // 3907
  const int NBUCK = (Nn + BR - 1) / BR;           // 3907 edge buckets
  const int NB_P = (Nn + CHUNK - 1) / CHUNK;      // 245 perm blocks

  const int* row = (const int*)d_in[0];
  const int* col = row + (size_t)E;

  int* out = (int*)d_out;
  int* A = out;                      // final: remaining rows
  int* B = out + (size_t)E;          // final: remaining cols
  int* C = out + (size_t)2 * E;      // final: masked rows
  int* D = out + (size_t)3 * E;      // final: masked cols
  int* M = out + (size_t)4 * E;      // final: edge_mask; staging: perm bufs + dstart
  uint64_t* U0 = (uint64_t*)out;                    // spans A+B (128MB)
  uint64_t* U1 = (uint64_t*)(out + (size_t)2 * E);  // spans C+D (128MB)
  // edge hist (4096*3907*4 = 64MB) lives in U1's bytes; fully consumed before
  // k_bucket256 writes sorted keys into U1.
  uint32_t* ehist = (uint32_t*)U1;

  // workspace carve (same proven budget)
  char* w = (char*)d_ws;
  uint64_t* hstage = (uint64_t*)w;            // 8,000,000 B (output phase only)
  int* rowptr = (int*)w;                      // 4,000,004 B (aliases hstage; dead after walk)
  w += (size_t)Nn * 8;
  uint8_t* hits = (uint8_t*)w; w += Nn;       // 1,000,000 B
  w = (char*)(((uintptr_t)w + 255) & ~(uintptr_t)255);
  uint32_t* bsums = (uint32_t*)w; w += (size_t)4096 * 4;
  uint32_t* scal = (uint32_t*)w;  w += 64;
  if ((size_t)(w - (char*)d_ws) > ws_size) return;  // insufficient scratch: fail visibly

  // staging inside M region (64 MB), all dead before M written in output phase:
  uint64_t* K64a  = (uint64_t*)M;                       // [0,  8MB)
  uint64_t* K64b  = (uint64_t*)(M + (size_t)2 * Nn);    // [8, 16MB)
  uint32_t* perm1 = (uint32_t*)(M + (size_t)4 * Nn);    // [16,20MB)
  uint32_t* startv= (uint32_t*)(M + (size_t)5 * Nn);    // [20,24MB)
  uint32_t* phist = (uint32_t*)(M + (size_t)6 * Nn);    // [24,28MB) perm hist ~1MB
  uint32_t* dstart= (uint32_t*)(M + (size_t)7 * Nn);    // [28MB+) 4097 u32

  // ---- host-side key derivation (JAX threefry, partitionable split = fold_in) ----
  struct KK { uint32_t a, b; };
  auto fold = [](KK k, uint32_t j) { KK r; tf2x32(k.a, k.b, 0u, j, &r.a, &r.b); return r; };
  KK base{0u, 42u};
  KK kperm = fold(base, 0u);
  KK kwalk = fold(base, 1u);
  KK keyA  = fold(kperm, 0u);
  KK sub1  = fold(kperm, 1u);
  KK sub2  = fold(keyA, 1u);
  KK wk0 = fold(kwalk, 0u), wk1 = fold(kwalk, 1u), wk2 = fold(kwalk, 2u);

  auto scan_u32 = [&](uint32_t* d, int n) {
    int SB = (n + CHUNK - 1) / CHUNK;
    k_sums_u32<<<SB, THREADS, 0, stream>>>(d, n, bsums);
    k_scan_single<<<1, THREADS, 0, stream>>>(bsums, SB, (uint32_t*)nullptr);
    k_excl_u32<<<SB, THREADS, 0, stream>>>(d, n, bsums);
  };

  hipMemsetAsync(hits, 0, (size_t)Nn, stream);

  // ---- 1) edge sort: hist + scan + capture starts + scatter + bucket sort ----
  k_hist12<<<NB_E, THREADS, 0, stream>>>(row, E, NB_E, ehist);
  scan_u32(ehist, EDIG * NB_E);
  k_dig_starts<<<(EDIG + 1 + THREADS - 1) / THREADS, THREADS, 0, stream>>>(
      ehist, NB_E, EDIG, E, dstart);
  k_pack_scatter12<<<NB_E, THREADS, 0, stream>>>(row, col, U0, ehist, E, NB_E);
  k_bucket256<<<NBUCK, THREADS, 0, stream>>>(U0, U1, dstart, E, Nn, rowptr);

  // ---- 2) permutation: 2 rounds of unique-key MSD + bitonic bucket sort ----
  k_genkeys64<<<NB_P, THREADS, 0, stream>>>(sub1.a, sub1.b, Nn, K64a, NB_P, phist);
  scan_u32(phist, PDIG * NB_P);
  k_dig_starts<<<(PDIG + 1 + THREADS - 1) / THREADS, THREADS, 0, stream>>>(
      phist, NB_P, PDIG, Nn, dstart);
  k_scatter64p<<<NB_P, THREADS, 0, stream>>>(K64a, K64b, phist, Nn, NB_P);
  k_psort<<<PDIG, THREADS, 0, stream>>>(K64b, dstart, perm1, (const uint32_t*)nullptr);
  k_genkeys64<<<NB_P, THREADS, 0, stream>>>(sub2.a, sub2.b, Nn, K64a, NB_P, phist);
  scan_u32(phist, PDIG * NB_P);
  k_dig_starts<<<(PDIG + 1 + THREADS - 1) / THREADS, THREADS, 0, stream>>>(
      phist, NB_P, PDIG, Nn, dstart);
  k_scatter64p<<<NB_P, THREADS, 0, stream>>>(K64a, K64b, phist, Nn, NB_P);
  k_psort<<<PDIG, THREADS, 0, stream>>>(K64b, dstart, startv, perm1);

  // ---- 3) random walks: mark hit nodes ----
  k_walk<<<(S + THREADS - 1) / THREADS, THREADS, 0, stream>>>(
      (const int*)startv, S, rowptr, U1, hits, wk0.a, wk0.b, wk1.a, wk1.b, wk2.a, wk2.b);

  // ---- 4) outputs: copy head + keep-scan, tail shift, head compaction, -1 fills ----
  k_mask_copy<<<NB_N, THREADS, 0, stream>>>(hits, U1, Nn, bsums, hstage);
  k_scan_single<<<1, THREADS, 0, stream>>>(bsums, NB_N, &scal[0]);   // scal[0] = keeps among i<Nn
  k_out_tail<<<4096, THREADS, 0, stream>>>(U1, E, Nn, &scal[0], A, B, M);
  k_out_headCD<<<NB_N, THREADS, 0, stream>>>(hstage, hits, Nn, bsums, A, B, C, D, M);
  k_cdfill<<<4096, THREADS, 0, stream>>>(E, Nn, &scal[0], A, B, C, D);
}

// Round 16
// 983.044 us; speedup vs baseline: 1.5575x; 1.0692x over previous
//
#include <hip/hip_runtime.h>
#include <stdint.h>

#define THREADS 256
#define ITEMS 16
#define CHUNK (THREADS * ITEMS)
#define COLMASK 0xFFFFFu
#define EDIG 4096      // edge scatter digits = row>>8
#define BR 256         // rows per edge bucket
#define BCAP 4608      // bucket capacity (avg 4096, +8 sigma)
#define PDIG 1024      // perm MSD digits

// ---------------- threefry2x32, JAX-compatible (20 rounds) ----------------
__host__ __device__ static inline void tf2x32(uint32_t k0, uint32_t k1,
                                              uint32_t x0, uint32_t x1,
                                              uint32_t* o0, uint32_t* o1) {
  uint32_t ks[3] = {k0, k1, k0 ^ k1 ^ 0x1BD11BDAu};
  x0 += ks[0]; x1 += ks[1];
  const uint32_t RA[4] = {13u, 15u, 26u, 6u};
  const uint32_t RB[4] = {17u, 29u, 16u, 24u};
#pragma unroll
  for (int g = 0; g < 5; ++g) {
    const uint32_t* R = (g & 1) ? RB : RA;
#pragma unroll
    for (int j = 0; j < 4; ++j) {
      x0 += x1;
      x1 = (x1 << R[j]) | (x1 >> (32u - R[j]));
      x1 ^= x0;
    }
    x0 += ks[(g + 1) % 3];
    x1 += ks[(g + 2) % 3] + (uint32_t)(g + 1);
  }
  *o0 = x0; *o1 = x1;
}

__device__ static inline uint32_t rbits32(uint32_t ka, uint32_t kb, uint32_t i) {
  uint32_t o0, o1;
  tf2x32(ka, kb, 0u, i, &o0, &o1);
  return o0 ^ o1;
}

// bijective XCD-aware block swizzle (m204 variant; works for any nwg)
__device__ static inline int xcd_swz(int orig, int nwg) {
  int q = nwg >> 3, r = nwg & 7;
  int xcd = orig & 7, idx = orig >> 3;
  return (xcd < r ? xcd * (q + 1) : r * (q + 1) + (xcd - r) * q) + idx;
}

// ---------------- block exclusive scan (all threads must call) ----------------
__device__ static inline uint32_t block_scan_excl(uint32_t v, uint32_t* lds) {
  int t = threadIdx.x;
  lds[t] = v;
  __syncthreads();
#pragma unroll
  for (int d = 1; d < THREADS; d <<= 1) {
    uint32_t add = (t >= d) ? lds[t - d] : 0u;
    __syncthreads();
    lds[t] += add;
    __syncthreads();
  }
  return lds[t] - v;
}

// ---------------- hierarchical scan helpers ----------------
__global__ void k_sums_u32(const uint32_t* __restrict__ d, int n, uint32_t* __restrict__ bsums) {
  __shared__ uint32_t lds[THREADS];
  int b = blockIdx.x, t = threadIdx.x;
  int base = b * CHUNK + t * ITEMS;
  uint32_t s = 0;
#pragma unroll
  for (int j = 0; j < ITEMS; ++j) { int i = base + j; if (i < n) s += d[i]; }
  lds[t] = s; __syncthreads();
  for (int d2 = THREADS / 2; d2 > 0; d2 >>= 1) { if (t < d2) lds[t] += lds[t + d2]; __syncthreads(); }
  if (t == 0) bsums[b] = lds[0];
}

__global__ void k_scan_single(uint32_t* __restrict__ d, int n, uint32_t* __restrict__ total_out) {
  __shared__ uint32_t lds[THREADS];
  int t = threadIdx.x;
  int K = (n + THREADS - 1) / THREADS;
  int s0 = t * K, s1 = (s0 + K < n) ? (s0 + K) : n;
  uint32_t s = 0;
  for (int j = s0; j < s1; ++j) s += d[j];
  lds[t] = s; __syncthreads();
#pragma unroll
  for (int dd = 1; dd < THREADS; dd <<= 1) {
    uint32_t a = (t >= dd) ? lds[t - dd] : 0u;
    __syncthreads();
    lds[t] += a;
    __syncthreads();
  }
  uint32_t incl = lds[t];
  if (total_out && t == THREADS - 1) *total_out = incl;
  uint32_t run = incl - s;
  for (int j = s0; j < s1; ++j) { uint32_t tmp = d[j]; d[j] = run; run += tmp; }
}

__global__ void k_excl_u32(uint32_t* __restrict__ d, int n, const uint32_t* __restrict__ bsums) {
  __shared__ uint32_t lds[THREADS];
  int b = blockIdx.x, t = threadIdx.x;
  int base = b * CHUNK + t * ITEMS;
  uint32_t v[ITEMS]; uint32_t s = 0;
#pragma unroll
  for (int j = 0; j < ITEMS; ++j) { int i = base + j; uint32_t x = (i < n) ? d[i] : 0u; v[j] = x; s += x; }
  uint32_t run = bsums[b] + block_scan_excl(s, lds);
#pragma unroll
  for (int j = 0; j < ITEMS; ++j) { int i = base + j; if (i < n) d[i] = run; run += v[j]; }
}

// capture per-digit global starts (hist[d*NB] after scan)
__global__ void k_dig_starts(const uint32_t* __restrict__ hist, int NB, int DIG, int total,
                             uint32_t* __restrict__ dstart) {
  int d = blockIdx.x * blockDim.x + threadIdx.x;
  if (d < DIG) dstart[d] = hist[(size_t)d * NB];
  else if (d == DIG) dstart[DIG] = (uint32_t)total;
}

// ---------------- edge pipeline: 1 unstable 12-bit pass + fused bucket sort ----------------
// R14 lesson: runtime atomic claims = 16M contended atomics (798us). R15 lesson: hist
// writes need the same xcd_swz as the scatter so each 64B hist line is written by
// one XCD's L2 (write-combining; 687->~150MB).
__global__ void k_hist12(const int* __restrict__ row, int n, int NB, uint32_t* __restrict__ hist) {
  __shared__ uint32_t h[EDIG];
  int b = xcd_swz(blockIdx.x, gridDim.x), t = threadIdx.x;
#pragma unroll
  for (int g = 0; g < EDIG / THREADS; ++g) h[g * THREADS + t] = 0;
  __syncthreads();
  int base = b * CHUNK;
  for (int j = t; j < CHUNK; j += THREADS) {
    int i = base + j;
    if (i < n) atomicAdd(&h[((uint32_t)row[i]) >> 8], 1u);
  }
  __syncthreads();
#pragma unroll
  for (int g = 0; g < EDIG / THREADS; ++g) {
    int d = g * THREADS + t;
    hist[(size_t)d * NB + b] = h[d];
  }
}

// pack (row<<20|col), unstable scatter by row>>8. gofs/lst in registers;
// cur[] reused as wofs behind a barrier (R12 lesson: no global reads in hot loop).
__global__ __launch_bounds__(THREADS) void k_pack_scatter12(
    const int* __restrict__ row, const int* __restrict__ col,
    uint64_t* __restrict__ kout, const uint32_t* __restrict__ hist, int n, int NB) {
  constexpr int G = EDIG / THREADS;   // 16
  __shared__ uint64_t lkeys[CHUNK];   // 32 KB (first 1 KB doubles as scan temp)
  __shared__ uint32_t cur[EDIG];      // 16 KB: counts -> cursors -> wofs
  int b = xcd_swz(blockIdx.x, gridDim.x), t = threadIdx.x;
  int base = b * CHUNK;
#pragma unroll
  for (int g = 0; g < G; ++g) cur[g * THREADS + t] = 0;
  __syncthreads();
  uint64_t mykey[ITEMS];
#pragma unroll
  for (int batch = 0; batch < ITEMS; ++batch) {
    int i = base + batch * THREADS + t;
    uint64_t key = 0ull;
    if (i < n) {
      uint32_t r = (uint32_t)row[i];
      key = ((uint64_t)r << 20) | (uint32_t)col[i];
      atomicAdd(&cur[r >> 8], 1u);
    }
    mykey[batch] = key;
  }
  __syncthreads();
  uint32_t c[G], go[G], lstv[G];
  uint32_t s = 0;
#pragma unroll
  for (int g = 0; g < G; ++g) { c[g] = cur[G * t + g]; s += c[g]; }
  uint32_t tp = block_scan_excl(s, (uint32_t*)lkeys);
  __syncthreads();   // scan temp (lkeys) fully consumed before reuse
#pragma unroll
  for (int g = 0; g < G; ++g) {
    int d = G * t + g;
    go[g] = hist[(size_t)d * NB + b];   // single strided read; L2-shared across blocks
    lstv[g] = tp;
    cur[d] = tp;
    tp += c[g];
  }
  __syncthreads();
#pragma unroll
  for (int batch = 0; batch < ITEMS; ++batch) {
    int i = base + batch * THREADS + t;
    if (i < n) {
      uint64_t key = mykey[batch];
      uint32_t dig = (uint32_t)(key >> 28);    // row>>8
      uint32_t slot = atomicAdd(&cur[dig], 1u);
      lkeys[slot] = key;
    }
  }
  __syncthreads();
#pragma unroll
  for (int g = 0; g < G; ++g) cur[G * t + g] = go[g] - lstv[g];  // wofs (u32 wrap-exact)
  __syncthreads();
  int nloc = n - base; if (nloc > CHUNK) nloc = CHUNK;
  for (int j = t; j < nloc; j += THREADS) {
    uint64_t key = lkeys[j];
    uint32_t dig = (uint32_t)(key >> 28);
    kout[cur[dig] + (uint32_t)j] = key;
  }
}

// one WG per 256-row bucket. Counting-sort into LDS, then RANK-based ordering
// (R15 lesson: per-thread insertion sort = serial divergent shifts + 1.8e7 bank
// conflicts; rank compute is flat, and consecutive lanes share a row so the inner
// lbuf[p] read is an LDS broadcast). Element j's final position = bs[row]+rank,
// rank = #{p in row : col[p]<col[j] || (col[p]==col[j] && p<j)}; direct global write.
__global__ __launch_bounds__(THREADS) void k_bucket256(
    const uint64_t* __restrict__ U0, uint64_t* __restrict__ U1,
    const uint32_t* __restrict__ dstart, int E, int Nn, int* __restrict__ rowptr) {
  __shared__ uint32_t lbuf[BCAP];     // 18 KB cols (first 1 KB doubles as scan temp)
  __shared__ uint8_t  rowof[BCAP];    // 4.5 KB row-id per slot
  __shared__ uint32_t cnt[BR];
  __shared__ uint32_t bs[BR + 1];
  int b = blockIdx.x, t = threadIdx.x;
  int s = (int)dstart[b];
  int e = (int)dstart[b + 1];
  int nseg = e - s;
  int r0 = b * BR;
  cnt[t] = 0;
  __syncthreads();
  for (int j = t; j < nseg; j += THREADS)
    atomicAdd(&cnt[(uint32_t)(U0[s + j] >> 20) & (BR - 1)], 1u);
  __syncthreads();
  uint32_t myc = cnt[t];
  uint32_t mybase = block_scan_excl(myc, lbuf);
  __syncthreads();   // scan temp fully consumed
  bs[t] = mybase;
  if (t == THREADS - 1) bs[BR] = mybase + myc;
  cnt[t] = mybase;   // cursor
  __syncthreads();
  if (nseg <= BCAP) {
    for (int j = t; j < nseg; j += THREADS) {
      uint64_t key = U0[s + j];   // L2-hot re-read
      uint32_t rl = (uint32_t)(key >> 20) & (BR - 1);
      uint32_t slot = atomicAdd(&cnt[rl], 1u);
      lbuf[slot] = (uint32_t)(key & COLMASK);
      rowof[slot] = (uint8_t)rl;
    }
    __syncthreads();
    // rank phase: flat, broadcast-friendly, no data movement in LDS
    for (int j = t; j < nseg; j += THREADS) {
      uint32_t key = lbuf[j];
      uint32_t rl = rowof[j];
      int a0 = (int)bs[rl], a1 = (int)bs[rl + 1];
      uint32_t rank = 0;
      for (int p = a0; p < a1; ++p) {
        uint32_t v = lbuf[p];   // lanes in same row read same addr -> broadcast
        rank += (v < key) || (v == key && p < j);
      }
      U1[s + a0 + (int)rank] = ((uint64_t)(uint32_t)(r0 + (int)rl) << 20) | key;
    }
  } else {
    // global fallback (statistically unreachable; correctness insurance)
    for (int j = t; j < nseg; j += THREADS) {
      uint64_t key = U0[s + j];
      uint32_t slot = atomicAdd(&cnt[(uint32_t)(key >> 20) & (BR - 1)], 1u);
      U1[s + slot] = key;
    }
    __syncthreads();
    int a0 = s + (int)bs[t], a1 = s + (int)bs[t + 1];
    for (int a = a0 + 1; a < a1; ++a) {
      uint64_t key = U1[a];
      int p = a - 1;
      while (p >= a0 && U1[p] > key) { U1[p + 1] = U1[p]; --p; }
      U1[p + 1] = key;
    }
  }
  int r = r0 + t;
  if (r < Nn) rowptr[r] = s + (int)bs[t];
  if (b == (int)gridDim.x - 1 && t == 0) rowptr[Nn] = E;
}

// ---------------- permutation: unique-key (bits<<20|i) MSD + per-bucket bitonic ----------------
__global__ void k_genkeys64(uint32_t ka, uint32_t kb, int n, uint64_t* __restrict__ K,
                            int NB, uint32_t* __restrict__ hist) {
  __shared__ uint32_t h[PDIG];
  int b = blockIdx.x, t = threadIdx.x;
#pragma unroll
  for (int g = 0; g < PDIG / THREADS; ++g) h[g * THREADS + t] = 0;
  __syncthreads();
  int base = b * CHUNK;
  for (int j = t; j < CHUNK; j += THREADS) {
    int i = base + j;
    if (i < n) {
      uint32_t rb = rbits32(ka, kb, (uint32_t)i);
      K[i] = ((uint64_t)rb << 20) | (uint32_t)i;
      atomicAdd(&h[rb >> 22], 1u);   // top 10 bits
    }
  }
  __syncthreads();
#pragma unroll
  for (int g = 0; g < PDIG / THREADS; ++g) {
    int d = g * THREADS + t;
    hist[(size_t)d * NB + b] = h[d];
  }
}

__global__ __launch_bounds__(THREADS) void k_scatter64p(
    const uint64_t* __restrict__ kin, uint64_t* __restrict__ kout,
    const uint32_t* __restrict__ hist, int n, int NB) {
  constexpr int G = PDIG / THREADS;   // 4
  __shared__ uint64_t lkeys[CHUNK];   // 32 KB
  __shared__ uint32_t cur[PDIG];      // 4 KB
  int b = blockIdx.x, t = threadIdx.x;
  int base = b * CHUNK;
#pragma unroll
  for (int g = 0; g < G; ++g) cur[g * THREADS + t] = 0;
  __syncthreads();
  uint64_t mykey[ITEMS];
#pragma unroll
  for (int batch = 0; batch < ITEMS; ++batch) {
    int i = base + batch * THREADS + t;
    uint64_t key = 0ull;
    if (i < n) {
      key = kin[i];
      atomicAdd(&cur[(uint32_t)(key >> 42)], 1u);
    }
    mykey[batch] = key;
  }
  __syncthreads();
  uint32_t c[G], go[G], lstv[G];
  uint32_t s = 0;
#pragma unroll
  for (int g = 0; g < G; ++g) { c[g] = cur[G * t + g]; s += c[g]; }
  uint32_t tp = block_scan_excl(s, (uint32_t*)lkeys);
  __syncthreads();
#pragma unroll
  for (int g = 0; g < G; ++g) {
    int d = G * t + g;
    go[g] = hist[(size_t)d * NB + b];
    lstv[g] = tp;
    cur[d] = tp;
    tp += c[g];
  }
  __syncthreads();
#pragma unroll
  for (int batch = 0; batch < ITEMS; ++batch) {
    int i = base + batch * THREADS + t;
    if (i < n) {
      uint64_t key = mykey[batch];
      uint32_t dig = (uint32_t)(key >> 42);
      uint32_t slot = atomicAdd(&cur[dig], 1u);
      lkeys[slot] = key;
    }
  }
  __syncthreads();
#pragma unroll
  for (int g = 0; g < G; ++g) cur[G * t + g] = go[g] - lstv[g];  // wofs
  __syncthreads();
  int nloc = n - base; if (nloc > CHUNK) nloc = CHUNK;
  for (int j = t; j < nloc; j += THREADS) {
    uint64_t key = lkeys[j];
    uint32_t dig = (uint32_t)(key >> 42);
    kout[cur[dig] + (uint32_t)j] = key;
  }
}

// per-bucket bitonic sort (2048-wide, padded with ~0). gsrc==null: out = low20 (perm1);
// else out = gsrc[low20] (round-2 payload gather).
__global__ __launch_bounds__(THREADS) void k_psort(
    const uint64_t* __restrict__ K, const uint32_t* __restrict__ dstart,
    uint32_t* __restrict__ outv, const uint32_t* __restrict__ gsrc) {
  __shared__ uint64_t sb[2048];   // 16 KB
  int b = blockIdx.x, t = threadIdx.x;
  int s = (int)dstart[b], e = (int)dstart[b + 1];
  int nseg = e - s;   // avg 977, sigma 31; 2048 = +34 sigma
  for (int j = t; j < 2048; j += THREADS)
    sb[j] = (j < nseg) ? K[s + j] : ~0ull;
  __syncthreads();
  for (int k = 2; k <= 2048; k <<= 1) {
    for (int j = k >> 1; j > 0; j >>= 1) {
      for (int i = t; i < 2048; i += THREADS) {
        int l = i ^ j;
        if (l > i) {
          bool up = ((i & k) == 0);
          uint64_t a = sb[i], c = sb[l];
          if ((a > c) == up) { sb[i] = c; sb[l] = a; }
        }
      }
      __syncthreads();
    }
  }
  for (int j = t; j < nseg; j += THREADS) {
    uint32_t p = (uint32_t)(sb[j] & COLMASK);
    outv[s + j] = gsrc ? gsrc[p] : p;
  }
}

// ---------------- random walks ----------------
__global__ void k_walk(const int* __restrict__ start, int S,
                       const int* __restrict__ rowptr, const uint64_t* __restrict__ U,
                       uint8_t* __restrict__ hits,
                       uint32_t k0a, uint32_t k0b, uint32_t k1a, uint32_t k1b,
                       uint32_t k2a, uint32_t k2b) {
  int i = blockIdx.x * blockDim.x + threadIdx.x;
  int st = gridDim.x * blockDim.x;
  for (; i < S; i += st) {
    int cur = start[i];
    bool active = true;
    uint32_t ka[3] = {k0a, k1a, k2a};
    uint32_t kb[3] = {k0b, k1b, k2b};
#pragma unroll
    for (int s = 0; s < 3; ++s) {
      int rp = rowptr[cur];
      int d = rowptr[cur + 1] - rp;
      bool act = active && (d > 0);
      if (act) hits[cur] = 1;
      uint32_t bits = rbits32(ka[s], kb[s], (uint32_t)i);
      float u = __uint_as_float((bits >> 9) | 0x3f800000u) - 1.0f;  // jax uniform [0,1)
      int off = (int)floorf(u * (float)d);
      int dm1 = d - 1; if (dm1 < 0) dm1 = 0;
      if (off > dm1) off = dm1;
      if (act) cur = (int)(U[rp + off] & COLMASK);
      active = act;
    }
  }
}

// ---------------- outputs (masked edges only exist at i < Nn) ----------------
__global__ void k_mask_copy(const uint8_t* __restrict__ hits, const uint64_t* __restrict__ U,
                            int Nn, uint32_t* __restrict__ bsums, uint64_t* __restrict__ hstage) {
  __shared__ uint32_t lds[THREADS];
  int b = blockIdx.x, t = threadIdx.x;
  int base = b * CHUNK + t * ITEMS;
  uint32_t s = 0;
#pragma unroll
  for (int j = 0; j < ITEMS; ++j) {
    int i = base + j;
    if (i < Nn) { s += (uint32_t)(!hits[i]); hstage[i] = U[i]; }
  }
  lds[t] = s; __syncthreads();
  for (int d2 = THREADS / 2; d2 > 0; d2 >>= 1) { if (t < d2) lds[t] += lds[t + d2]; __syncthreads(); }
  if (t == 0) bsums[b] = lds[0];
}

__global__ void k_out_tail(const uint64_t* __restrict__ U, int E, int Nn,
                           const uint32_t* __restrict__ keephead,
                           int* __restrict__ A, int* __restrict__ B, int* __restrict__ M) {
  int nm = Nn - (int)*keephead;
  int i = Nn + blockIdx.x * blockDim.x + threadIdx.x;
  int st = gridDim.x * blockDim.x;
  for (; i < E; i += st) {
    uint64_t key = U[i];
    A[i - nm] = (int)(key >> 20);
    B[i - nm] = (int)(key & COLMASK);
    M[i] = 1;
  }
}

__global__ void k_out_headCD(const uint64_t* __restrict__ hstage, const uint8_t* __restrict__ hits,
                             int Nn, const uint32_t* __restrict__ bsums,
                             int* __restrict__ A, int* __restrict__ B,
                             int* __restrict__ C, int* __restrict__ D, int* __restrict__ M) {
  __shared__ uint32_t lds[THREADS];
  int b = blockIdx.x, t = threadIdx.x;
  int base = b * CHUNK + t * ITEMS;
  uint32_t keep[ITEMS]; uint32_t s = 0;
#pragma unroll
  for (int j = 0; j < ITEMS; ++j) {
    int i = base + j;
    uint32_t k = (i < Nn) ? (uint32_t)(!hits[i]) : 0u;
    keep[j] = k; s += k;
  }
  uint32_t kr = bsums[b] + block_scan_excl(s, lds);
#pragma unroll
  for (int j = 0; j < ITEMS; ++j) {
    int i = base + j;
    if (i < Nn) {
      uint64_t key = hstage[i];
      if (keep[j]) { A[kr] = (int)(key >> 20); B[kr] = (int)(key & COLMASK); M[i] = 1; ++kr; }
      else { uint32_t mr = (uint32_t)i - kr; C[mr] = (int)(key >> 20); D[mr] = (int)(key & COLMASK); M[i] = 0; }
    }
  }
}

__global__ void k_cdfill(int E, int Nn, const uint32_t* __restrict__ keephead,
                         int* __restrict__ A, int* __restrict__ B,
                         int* __restrict__ C, int* __restrict__ D) {
  int nm = Nn - (int)*keephead;
  int j = blockIdx.x * blockDim.x + threadIdx.x;
  int st = gridDim.x * blockDim.x;
  for (; j < E; j += st) {
    if (j >= nm) { C[j] = -1; D[j] = -1; }
    if (j >= E - nm) { A[j] = -1; B[j] = -1; }
  }
}

// ---------------- launcher ----------------
extern "C" void kernel_launch(void* const* d_in, const int* in_sizes, int n_in,
                              void* d_out, int out_size, void* d_ws, size_t ws_size,
                              hipStream_t stream) {
  const int E = in_sizes[0] / 2;
  const int Nn = 1000000;   // num_nodes (fixed problem)
  const int S = 700000;     // round(0.7*N) * WALKS_PER_NODE
  const int NB_N = (Nn + CHUNK - 1) / CHUNK;      // 245
  const int NB_E = (E + CHUNK - 1) / CHUNK;       // 3907
  const int NBUCK = (Nn + BR - 1) / BR;           // 3907 edge buckets
  const int NB_P = (Nn + CHUNK - 1) / CHUNK;      // 245 perm blocks

  const int* row = (const int*)d_in[0];
  const int* col = row + (size_t)E;

  int* out = (int*)d_out;
  int* A = out;                      // final: remaining rows
  int* B = out + (size_t)E;          // final: remaining cols
  int* C = out + (size_t)2 * E;      // final: masked rows
  int* D = out + (size_t)3 * E;      // final: masked cols
  int* M = out + (size_t)4 * E;      // final: edge_mask; staging: perm bufs + dstart
  uint64_t* U0 = (uint64_t*)out;                    // spans A+B (128MB)
  uint64_t* U1 = (uint64_t*)(out + (size_t)2 * E);  // spans C+D (128MB)
  // edge hist (4096*3907*4 = 64MB) lives in U1's bytes; fully consumed before
  // k_bucket256 writes sorted keys into U1.
  uint32_t* ehist = (uint32_t*)U1;

  // workspace carve (same proven budget)
  char* w = (char*)d_ws;
  uint64_t* hstage = (uint64_t*)w;            // 8,000,000 B (output phase only)
  int* rowptr = (int*)w;                      // 4,000,004 B (aliases hstage; dead after walk)
  w += (size_t)Nn * 8;
  uint8_t* hits = (uint8_t*)w; w += Nn;       // 1,000,000 B
  w = (char*)(((uintptr_t)w + 255) & ~(uintptr_t)255);
  uint32_t* bsums = (uint32_t*)w; w += (size_t)4096 * 4;
  uint32_t* scal = (uint32_t*)w;  w += 64;
  if ((size_t)(w - (char*)d_ws) > ws_size) return;  // insufficient scratch: fail visibly

  // staging inside M region (64 MB), all dead before M written in output phase:
  uint64_t* K64a  = (uint64_t*)M;                       // [0,  8MB)
  uint64_t* K64b  = (uint64_t*)(M + (size_t)2 * Nn);    // [8, 16MB)
  uint32_t* perm1 = (uint32_t*)(M + (size_t)4 * Nn);    // [16,20MB)
  uint32_t* startv= (uint32_t*)(M + (size_t)5 * Nn);    // [20,24MB)
  uint32_t* phist = (uint32_t*)(M + (size_t)6 * Nn);    // [24,28MB) perm hist ~1MB
  uint32_t* dstart= (uint32_t*)(M + (size_t)7 * Nn);    // [28MB+) 4097 u32

  // ---- host-side key derivation (JAX threefry, partitionable split = fold_in) ----
  struct KK { uint32_t a, b; };
  auto fold = [](KK k, uint32_t j) { KK r; tf2x32(k.a, k.b, 0u, j, &r.a, &r.b); return r; };
  KK base{0u, 42u};
  KK kperm = fold(base, 0u);
  KK kwalk = fold(base, 1u);
  KK keyA  = fold(kperm, 0u);
  KK sub1  = fold(kperm, 1u);
  KK sub2  = fold(keyA, 1u);
  KK wk0 = fold(kwalk, 0u), wk1 = fold(kwalk, 1u), wk2 = fold(kwalk, 2u);

  auto scan_u32 = [&](uint32_t* d, int n) {
    int SB = (n + CHUNK - 1) / CHUNK;
    k_sums_u32<<<SB, THREADS, 0, stream>>>(d, n, bsums);
    k_scan_single<<<1, THREADS, 0, stream>>>(bsums, SB, (uint32_t*)nullptr);
    k_excl_u32<<<SB, THREADS, 0, stream>>>(d, n, bsums);
  };

  hipMemsetAsync(hits, 0, (size_t)Nn, stream);

  // ---- 1) edge sort: hist + scan + capture starts + scatter + bucket sort ----
  k_hist12<<<NB_E, THREADS, 0, stream>>>(row, E, NB_E, ehist);
  scan_u32(ehist, EDIG * NB_E);
  k_dig_starts<<<(EDIG + 1 + THREADS - 1) / THREADS, THREADS, 0, stream>>>(
      ehist, NB_E, EDIG, E, dstart);
  k_pack_scatter12<<<NB_E, THREADS, 0, stream>>>(row, col, U0, ehist, E, NB_E);
  k_bucket256<<<NBUCK, THREADS, 0, stream>>>(U0, U1, dstart, E, Nn, rowptr);

  // ---- 2) permutation: 2 rounds of unique-key MSD + bitonic bucket sort ----
  k_genkeys64<<<NB_P, THREADS, 0, stream>>>(sub1.a, sub1.b, Nn, K64a, NB_P, phist);
  scan_u32(phist, PDIG * NB_P);
  k_dig_starts<<<(PDIG + 1 + THREADS - 1) / THREADS, THREADS, 0, stream>>>(
      phist, NB_P, PDIG, Nn, dstart);
  k_scatter64p<<<NB_P, THREADS, 0, stream>>>(K64a, K64b, phist, Nn, NB_P);
  k_psort<<<PDIG, THREADS, 0, stream>>>(K64b, dstart, perm1, (const uint32_t*)nullptr);
  k_genkeys64<<<NB_P, THREADS, 0, stream>>>(sub2.a, sub2.b, Nn, K64a, NB_P, phist);
  scan_u32(phist, PDIG * NB_P);
  k_dig_starts<<<(PDIG + 1 + THREADS - 1) / THREADS, THREADS, 0, stream>>>(
      phist, NB_P, PDIG, Nn, dstart);
  k_scatter64p<<<NB_P, THREADS, 0, stream>>>(K64a, K64b, phist, Nn, NB_P);
  k_psort<<<PDIG, THREADS, 0, stream>>>(K64b, dstart, startv, perm1);

  // ---- 3) random walks: mark hit nodes ----
  k_walk<<<(S + THREADS - 1) / THREADS, THREADS, 0, stream>>>(
      (const int*)startv, S, rowptr, U1, hits, wk0.a, wk0.b, wk1.a, wk1.b, wk2.a, wk2.b);

  // ---- 4) outputs: copy head + keep-scan, tail shift, head compaction, -1 fills ----
  k_mask_copy<<<NB_N, THREADS, 0, stream>>>(hits, U1, Nn, bsums, hstage);
  k_scan_single<<<1, THREADS, 0, stream>>>(bsums, NB_N, &scal[0]);   // scal[0] = keeps among i<Nn
  k_out_tail<<<4096, THREADS, 0, stream>>>(U1, E, Nn, &scal[0], A, B, M);
  k_out_headCD<<<NB_N, THREADS, 0, stream>>>(hstage, hits, Nn, bsums, A, B, C, D, M);
  k_cdfill<<<4096, THREADS, 0, stream>>>(E, Nn, &scal[0], A, B, C, D);
}